// Round 8
// baseline (66.024 us; speedup 1.0000x reference)
//
#include <hip/hip_runtime.h>

// Integrate-and-fire over T=4 timesteps, fp32.
// x viewed as [T, S], S = B*C*H*W. Thread i owns vec4 index i (unit lane
// stride -> contiguous 1KB wave loads/stores). Scan per element:
//   mem += x_t; spike = (mem >= thre) ? thre : 0; mem -= spike
//
// Cache policy — INVERTED vs R4 (the discriminating experiment):
//  - out stores: NORMAL. out is 205 MB < 256 MB Infinity Cache; each
//    graph replay rewrites the same lines in-cache -> dirty-resident,
//    ~zero HBM writeback in steady state (full-line wave stores, no RFO;
//    fills prove normal writes sustain 7 TB/s).
//  - x loads: non-temporal. x must not compete with out for L3; reads
//    stream from HBM (~205 MB/replay).
// Per-replay HBM: ~205 MB read + conflict writebacks, vs R4's 301 MB
// (100 MB read-miss + 201 MB write). If WRITE_SIZE does not collapse,
// the MALL ignores the policy and R7 (62.9 us) is the roofline.

typedef float vfloat4 __attribute__((ext_vector_type(4)));

#define IF_STEP(m, xv, sv) { (m) += (xv); (sv) = ((m) >= thre) ? thre : 0.0f; (m) -= (sv); }

__global__ __launch_bounds__(256) void if_scan_kernel(
    const float* __restrict__ x,
    const float* __restrict__ thresh,
    float* __restrict__ out,
    long long n4)        // vec4 count per timestep slab = S/4
{
    const float thre = thresh[0];
    const float half = 0.5f * thre;
    const long long s = n4;  // timestep stride in vec4 units

    const vfloat4* __restrict__ x4 = reinterpret_cast<const vfloat4*>(x);
    vfloat4* __restrict__ o4 = reinterpret_cast<vfloat4*>(out);

    const long long gsz = (long long)gridDim.x * blockDim.x;
    long long i = (long long)blockIdx.x * blockDim.x + threadIdx.x;

    for (; i < n4; i += gsz) {
        // 4 independent nt loads issued up front (stream, no L3 alloc)
        vfloat4 x0 = __builtin_nontemporal_load(&x4[i + 0 * s]);
        vfloat4 x1 = __builtin_nontemporal_load(&x4[i + 1 * s]);
        vfloat4 x2 = __builtin_nontemporal_load(&x4[i + 2 * s]);
        vfloat4 x3 = __builtin_nontemporal_load(&x4[i + 3 * s]);

        vfloat4 s0, s1, s2, s3;
        #pragma unroll
        for (int c = 0; c < 4; ++c) {
            float m = half;
            IF_STEP(m, x0[c], s0[c]);
            IF_STEP(m, x1[c], s1[c]);
            IF_STEP(m, x2[c], s2[c]);
            IF_STEP(m, x3[c], s3[c]);
        }

        // normal stores: out allocates and stays dirty-resident in L3
        o4[i + 0 * s] = s0;
        o4[i + 1 * s] = s1;
        o4[i + 2 * s] = s2;
        o4[i + 3 * s] = s3;
    }
}

extern "C" void kernel_launch(void* const* d_in, const int* in_sizes, int n_in,
                              void* d_out, int out_size, void* d_ws, size_t ws_size,
                              hipStream_t stream) {
    const float* x = (const float*)d_in[0];
    const float* thresh = (const float*)d_in[1];
    float* out = (float*)d_out;

    const long long n_total = (long long)in_sizes[0];  // T * B * C * H * W
    const int T = 4;
    const long long n_spatial = n_total / T;           // B*C*H*W
    const long long n4 = n_spatial / 4;                // vec4 per slab

    const int block = 256;
    long long blocks_needed = (n4 + block - 1) / block;
    int grid = (int)((blocks_needed < 2048) ? blocks_needed : 2048);
    if (grid < 1) grid = 1;

    if_scan_kernel<<<grid, block, 0, stream>>>(x, thresh, out, n4);
}

// Round 9
// 62.763 us; speedup vs baseline: 1.0520x; 1.0520x over previous
//
#include <hip/hip_runtime.h>

// FINAL (R7 config, 62.9 us): Integrate-and-fire over T=4 timesteps, fp32.
// x viewed as [T, S], S = B*C*H*W. Block-stride 2x unroll, unit lane
// stride (contiguous 1KB wave loads/stores). Scan per element:
//   mem += x_t; spike = (mem >= thre) ? thre : 0; mem -= spike
//
// Cache policy (settled by R3-R8 experiments):
//  - x loads NORMAL: L3 serves ~105 MB/replay of the 205 MB read stream
//    (nt loads forfeit this: R5 +4.4us, R8 +3.1us).
//  - out stores builtin-nt: keeps the 201 MB write stream from evicting
//    x in L3 (normal stores: FETCH 205 MB; nt: FETCH 100 MB).
//  - inline-asm sc0/sc1/nt stores corrupt data (no vmcnt modeling of asm
//    VMEM; compiler reuses store-source VGPRs) — do not retry.
// Effective 6.54 TB/s (411 MB logical / 62.9 us) = above float4-copy
// ceiling (6.29), 93% of write-only fill ceiling. Roofline.

typedef float vfloat4 __attribute__((ext_vector_type(4)));

#define IF_STEP(m, xv, sv) { (m) += (xv); (sv) = ((m) >= thre) ? thre : 0.0f; (m) -= (sv); }

__global__ __launch_bounds__(256) void if_scan_kernel(
    const float* __restrict__ x,
    const float* __restrict__ thresh,
    float* __restrict__ out,
    long long n4)        // vec4 count per timestep slab = S/4
{
    const float thre = thresh[0];
    const float half = 0.5f * thre;
    const long long s = n4;  // timestep stride in vec4 units

    const vfloat4* __restrict__ x4 = reinterpret_cast<const vfloat4*>(x);
    vfloat4* __restrict__ o4 = reinterpret_cast<vfloat4*>(out);

    const long long step = (long long)gridDim.x * blockDim.x * 2;
    long long i = (long long)blockIdx.x * (blockDim.x * 2) + threadIdx.x;

    for (; i < n4; i += step) {
        const long long iB = i + blockDim.x;   // second tile, 256 vec4 away
        const bool hasB = iB < n4;

        // issue all loads up front (8 independent VMEM ops in flight)
        vfloat4 a0 = x4[i + 0 * s];
        vfloat4 a1 = x4[i + 1 * s];
        vfloat4 a2 = x4[i + 2 * s];
        vfloat4 a3 = x4[i + 3 * s];
        vfloat4 b0, b1, b2, b3;
        if (hasB) {
            b0 = x4[iB + 0 * s];
            b1 = x4[iB + 1 * s];
            b2 = x4[iB + 2 * s];
            b3 = x4[iB + 3 * s];
        }

        vfloat4 ra0, ra1, ra2, ra3;
        #pragma unroll
        for (int c = 0; c < 4; ++c) {
            float m = half;
            IF_STEP(m, a0[c], ra0[c]);
            IF_STEP(m, a1[c], ra1[c]);
            IF_STEP(m, a2[c], ra2[c]);
            IF_STEP(m, a3[c], ra3[c]);
        }
        __builtin_nontemporal_store(ra0, &o4[i + 0 * s]);
        __builtin_nontemporal_store(ra1, &o4[i + 1 * s]);
        __builtin_nontemporal_store(ra2, &o4[i + 2 * s]);
        __builtin_nontemporal_store(ra3, &o4[i + 3 * s]);

        if (hasB) {
            vfloat4 rb0, rb1, rb2, rb3;
            #pragma unroll
            for (int c = 0; c < 4; ++c) {
                float m = half;
                IF_STEP(m, b0[c], rb0[c]);
                IF_STEP(m, b1[c], rb1[c]);
                IF_STEP(m, b2[c], rb2[c]);
                IF_STEP(m, b3[c], rb3[c]);
            }
            __builtin_nontemporal_store(rb0, &o4[iB + 0 * s]);
            __builtin_nontemporal_store(rb1, &o4[iB + 1 * s]);
            __builtin_nontemporal_store(rb2, &o4[iB + 2 * s]);
            __builtin_nontemporal_store(rb3, &o4[iB + 3 * s]);
        }
    }
}

extern "C" void kernel_launch(void* const* d_in, const int* in_sizes, int n_in,
                              void* d_out, int out_size, void* d_ws, size_t ws_size,
                              hipStream_t stream) {
    const float* x = (const float*)d_in[0];
    const float* thresh = (const float*)d_in[1];
    float* out = (float*)d_out;

    const long long n_total = (long long)in_sizes[0];  // T * B * C * H * W
    const int T = 4;
    const long long n_spatial = n_total / T;           // B*C*H*W
    const long long n4 = n_spatial / 4;                // vec4 per slab

    const int block = 256;
    // full coverage in one pass: each block handles 2*block vec4 per slab
    long long blocks_needed = (n4 + (long long)block * 2 - 1) / ((long long)block * 2);
    int grid = (int)blocks_needed;   // 6272 for the bench shape
    if (grid < 1) grid = 1;

    if_scan_kernel<<<grid, block, 0, stream>>>(x, thresh, out, n4);
}